// Round 5
// baseline (594.409 us; speedup 1.0000x reference)
//
#include <hip/hip_runtime.h>
#include <math.h>

#define NN    4096
#define KK    20
#define SUBS  8
#define PPB   64
#define BLK   (PPB*SUBS)        // 512 threads, 8 waves
#define TILE  512
#define NT    (NN/TILE)         // 8 tiles
#define CHUNK (TILE/SUBS)       // 64 points per sub per tile (stride-8 slice)
#define M     6                 // per-sub short-list (8*6=48 >= 21)
#define CAP   48                // per-point candidate capacity
#define CROW  49                // padded row stride
#define BPB   (NN/PPB)          // 64 blocks per batch

__global__ __launch_bounds__(BLK, 4)
void edgeconv_kernel(const float* __restrict__ x,
                     const float* __restrict__ W,
                     const float* __restrict__ bias,
                     float* __restrict__ out) {
  __shared__ __align__(16) float tiles[2][TILE * 4];   // (x,y,z,|x|^2): 16 KB dbuf
  __shared__ float smin[PPB][CROW];                    // top-6 lists; reused as jkeep
  __shared__ float dcand[PPB][CROW];
  __shared__ int   jcand[PPB][CROW];
  __shared__ int   pc[PPB];
  __shared__ int   pk[PPB];

  const int tid  = threadIdx.x;
  const int g    = tid >> 3;          // point group 0..63
  const int s    = tid & 7;           // sub-scanner 0..7
  const int bb   = blockIdx.x / BPB;
  const int blk  = blockIdx.x % BPB;
  const int base = bb * NN;
  const int myp  = blk * PPB + g;

  const float mx = x[(size_t)(base + myp) * 3 + 0];
  const float my = x[(size_t)(base + myp) * 3 + 1];
  const float mz = x[(size_t)(base + myp) * 3 + 2];
  // d' = sq_j - 2*xi.xj = dist2 - |xi|^2 (order-preserving per point)
  const float nx = -2.f * mx, ny = -2.f * my, nz = -2.f * mz;

  // ---- stage tile 0: (x,y,z,sq) per point, one point per thread ------------
  {
    const float* p = x + (size_t)(base + tid) * 3;
    const float a = p[0], b2 = p[1], c = p[2];
    float4 w4; w4.x = a; w4.y = b2; w4.z = c; w4.w = fmaf(c, c, fmaf(b2, b2, a * a));
    ((float4*)tiles[0])[tid] = w4;
  }
  __syncthreads();

  float nd[M];                                         // descending: nd[0]=max
  #pragma unroll
  for (int i = 0; i < M; ++i) nd[i] = INFINITY;

  // ---------------- Phase A: per-sub top-6 d' values (self rides along) -----
  {
    int cur = 0;
    for (int t = 0; t < NT; ++t) {
      float pa, pb, pcf;
      const bool more = (t + 1 < NT);
      if (more) {
        const float* p = x + (size_t)(base + (t + 1) * TILE + tid) * 3;
        pa = p[0]; pb = p[1]; pcf = p[2];
      }
      const float* tp = tiles[cur] + s * 4;   // sub s: points s, s+8, ... (bank 4s)
      #pragma unroll
      for (int i = 0; i < CHUNK; ++i) {
        const float4 v = *(const float4*)(tp + i * 32);
        const float d = fmaf(nx, v.x, fmaf(ny, v.y, fmaf(nz, v.z, v.w)));
        #pragma unroll
        for (int t2 = 0; t2 < M - 1; ++t2)     // sorted insert: med3 ladder
          nd[t2] = __builtin_amdgcn_fmed3f(nd[t2], nd[t2 + 1], d);
        nd[M - 1] = fminf(nd[M - 1], d);
      }
      if (more) {
        float4 w4; w4.x = pa; w4.y = pb; w4.z = pcf;
        w4.w = fmaf(pcf, pcf, fmaf(pb, pb, pa * pa));
        ((float4*)tiles[cur ^ 1])[tid] = w4;
        __syncthreads();
        cur ^= 1;
      }
    }
  }
  #pragma unroll
  for (int i = 0; i < M; ++i) smin[g][s * M + i] = nd[M - 1 - i];  // ascending
  __syncthreads();

  // restage tile 0 (loads overlap the merge below) + zero counters
  float pa0, pb0, pc0;
  {
    const float* p = x + (size_t)(base + tid) * 3;
    pa0 = p[0]; pb0 = p[1]; pc0 = p[2];
  }
  if (tid < PPB) { pc[tid] = 0; pk[tid] = 0; }

  // ---- Merge: tau_hat = 21st smallest of 48-union (>= true tau; one self) --
  float tau;
  {
    const float* L = &smin[g][0];
    float h0 = L[0*M], h1 = L[1*M], h2 = L[2*M], h3 = L[3*M];
    float h4 = L[4*M], h5 = L[5*M], h6 = L[6*M], h7 = L[7*M];
    int i0=0,i1=0,i2=0,i3=0,i4=0,i5=0,i6=0,i7=0;
    float mm = 0.f;
    for (int r = 0; r <= KK; ++r) {                    // 21 rounds
      mm = fminf(fminf(fminf(h0,h1),fminf(h2,h3)),fminf(fminf(h4,h5),fminf(h6,h7)));
      bool done = false, tk;
      tk = (h0==mm);           if (tk){++i0; h0=(i0<M)?L[0*M+i0]:INFINITY;} done|=tk;
      tk = (!done && h1==mm);  if (tk){++i1; h1=(i1<M)?L[1*M+i1]:INFINITY;} done|=tk;
      tk = (!done && h2==mm);  if (tk){++i2; h2=(i2<M)?L[2*M+i2]:INFINITY;} done|=tk;
      tk = (!done && h3==mm);  if (tk){++i3; h3=(i3<M)?L[3*M+i3]:INFINITY;} done|=tk;
      tk = (!done && h4==mm);  if (tk){++i4; h4=(i4<M)?L[4*M+i4]:INFINITY;} done|=tk;
      tk = (!done && h5==mm);  if (tk){++i5; h5=(i5<M)?L[5*M+i5]:INFINITY;} done|=tk;
      tk = (!done && h6==mm);  if (tk){++i6; h6=(i6<M)?L[6*M+i6]:INFINITY;} done|=tk;
      tk = (!done && h7==mm);  if (tk){++i7; h7=(i7<M)?L[7*M+i7]:INFINITY;} done|=tk;
    }
    tau = mm;
  }
  {
    float4 w4; w4.x = pa0; w4.y = pb0; w4.z = pc0;
    w4.w = fmaf(pc0, pc0, fmaf(pb0, pb0, pa0 * pa0));
    ((float4*)tiles[0])[tid] = w4;
  }
  __syncthreads();   // tile 0 staged, counters zeroed, smin reads done

  // ---------------- Phase B: collect candidates d' <= tau (self included) ---
  {
    int cur = 0;
    for (int t = 0; t < NT; ++t) {
      float pa, pb, pcf;
      const bool more = (t + 1 < NT);
      if (more) {
        const float* p = x + (size_t)(base + (t + 1) * TILE + tid) * 3;
        pa = p[0]; pb = p[1]; pcf = p[2];
      }
      const float* tp = tiles[cur] + s * 4;
      const int jg0 = t * TILE + s;
      #pragma unroll
      for (int i = 0; i < CHUNK; ++i) {
        const float4 v = *(const float4*)(tp + i * 32);
        const float d = fmaf(nx, v.x, fmaf(ny, v.y, fmaf(nz, v.z, v.w)));
        if (d <= tau) {
          int w = atomicAdd(&pc[g], 1);
          if (w < CAP) { dcand[g][w] = d; jcand[g][w] = jg0 + 8 * i; }
        }
      }
      if (more) {
        float4 w4; w4.x = pa; w4.y = pb; w4.z = pcf;
        w4.w = fmaf(pcf, pcf, fmaf(pb, pb, pa * pa));
        ((float4*)tiles[cur ^ 1])[tid] = w4;
        __syncthreads();
        cur ^= 1;
      }
    }
  }
  __syncthreads();

  // ---- Rank + compact: keep j!=self with lex-rank(d,j) < 21 (exactly 20) ---
  int (*jkeep)[CROW] = (int(*)[CROW])smin;             // smin dead after merge
  {
    const int n0 = pc[g];
    const int n = n0 < CAP ? n0 : CAP;
    for (int k = s; k < n; k += SUBS) {
      const float dk = dcand[g][k];
      const int   jk = jcand[g][k];
      int rank = 0;
      for (int k2 = 0; k2 < n; ++k2) {
        const float d2 = dcand[g][k2];
        const int   j2 = jcand[g][k2];
        rank += (d2 < dk || (d2 == dk && j2 < jk)) ? 1 : 0;
      }
      if (jk != myp && rank < KK + 1) {
        const int w = atomicAdd(&pk[g], 1);
        jkeep[g][w] = jk;                              // set is deterministic
      }
    }
  }
  __syncthreads();

  // ---------------- Feature phase: lane = channel; h = xj.w345 + const_i ----
  const int wv   = tid >> 6;
  const int lane = tid & 63;
  const float w3 = W[3*64+lane], w4 = W[4*64+lane], w5 = W[5*64+lane];
  const float c0 = W[0*64+lane] - w3;
  const float c1 = W[1*64+lane] - w4;
  const float c2 = W[2*64+lane] - w5;
  const float bo = bias[lane];

  for (int pi = 0; pi < PPB / 8; ++pi) {       // 8 points per wave
    const int p   = wv * (PPB / 8) + pi;
    const int pid = blk * PPB + p;
    const float* xi = x + (size_t)(base + pid) * 3;
    const float ci = fmaf(xi[0], c0, fmaf(xi[1], c1, fmaf(xi[2], c2, bo)));
    float hmax = -INFINITY;
    #pragma unroll
    for (int k = 0; k < KK; ++k) {             // exactly 20, wave-uniform
      const int j = jkeep[p][k];
      const float* xp = x + (size_t)(base + j) * 3;
      hmax = fmaxf(hmax, fmaf(xp[0], w3, fmaf(xp[1], w4, fmaf(xp[2], w5, ci))));
    }
    out[(size_t)(base + pid) * 64 + lane] = fmaxf(hmax, 0.0f);
  }
}

extern "C" void kernel_launch(void* const* d_in, const int* in_sizes, int n_in,
                              void* d_out, int out_size, void* d_ws, size_t ws_size,
                              hipStream_t stream) {
  const float* x  = (const float*)d_in[0];
  // d_in[1] = batch (implicit: i / N) — unused
  const float* W  = (const float*)d_in[2];
  const float* b  = (const float*)d_in[3];
  float* out = (float*)d_out;

  dim3 grid(8 * BPB);   // 512 blocks: 8 batches x 64 point-groups
  dim3 block(BLK);
  hipLaunchKernelGGL(edgeconv_kernel, grid, block, 0, stream, x, W, b, out);
}

// Round 6
// 111.933 us; speedup vs baseline: 5.3104x; 5.3104x over previous
//
#include <hip/hip_runtime.h>
#include <math.h>

#define NN    4096
#define KK    20
#define SUBS  16
#define PPB   32
#define BLK   (PPB*SUBS)        // 512 threads, 8 waves
#define TILE  512
#define NT    (NN/TILE)         // 8 tiles
#define CHUNK (TILE/SUBS)       // 32 points per sub per tile
#define M     3                 // per-sub short-list (16*3=48 >= 21)
#define CAP   48                // per-point candidate capacity
#define CROW  49                // padded row stride
#define BPB   (NN/PPB)          // 128 blocks per batch

__device__ __forceinline__ float dist2(float ax, float ay, float az,
                                       float bx, float by, float bz) {
  float dx = ax - bx, dy = ay - by, dz = az - bz;
  return fmaf(dx, dx, fmaf(dy, dy, dz * dz));
}

__global__ __launch_bounds__(BLK, 2)
void edgeconv_kernel(const float* __restrict__ x,
                     const float* __restrict__ W,
                     const float* __restrict__ bias,
                     float* __restrict__ out) {
  __shared__ __align__(16) float tiles[2][TILE * 3];   // 12 KB double-buffered AoS
  __shared__ float smin[PPB][CROW];                    // top-3 lists; reused as jkeep
  __shared__ float dcand[PPB][CROW];
  __shared__ int   jcand[PPB][CROW];
  __shared__ float taub[PPB];
  __shared__ int   pc[PPB];
  __shared__ int   pk[PPB];

  const int tid  = threadIdx.x;
  const int g    = tid >> 4;          // point group 0..31
  const int s    = tid & 15;          // sub-scanner 0..15
  const int bb   = blockIdx.x / BPB;
  const int blk  = blockIdx.x % BPB;
  const int base = bb * NN;
  const int myp  = blk * PPB + g;

  const float mx = x[(size_t)(base + myp) * 3 + 0];
  const float my = x[(size_t)(base + myp) * 3 + 1];
  const float mz = x[(size_t)(base + myp) * 3 + 2];

  const bool has = (tid < TILE * 3 / 4);               // 384 staging threads
  const float4* gx0 = (const float4*)(x + (size_t)base * 3);

  float nd[M];                                         // descending: nd[0]=max
  #pragma unroll
  for (int i = 0; i < M; ++i) nd[i] = INFINITY;

  // branchless sorted insert: max(nd[t+1], min(nd[t], d)) == med3 given order
  auto ins = [&](float d) {
    #pragma unroll
    for (int t2 = 0; t2 < M - 1; ++t2)
      nd[t2] = __builtin_amdgcn_fmed3f(nd[t2], nd[t2 + 1], d);
    nd[M - 1] = fminf(nd[M - 1], d);
  };

  // Sub s starts its chunk at q0 = 4*s (wrap): start banks of the 16 b128
  // reads tile the 32 banks uniformly 2-way (free per m136).
  const int q0 = (4 * s) & (CHUNK - 1);

  // ---------------- Phase A: per-sub top-3 VALUES (self d=0 rides along) -----
  if (has) ((float4*)tiles[0])[tid] = gx0[tid];
  __syncthreads();
  {
    int cur = 0;
    for (int t = 0; t < NT; ++t) {
      float4 rn;
      const bool more = (t + 1 < NT);
      if (more && has) rn = gx0[(t + 1) * (TILE * 3 / 4) + tid];
      const float* tp = tiles[cur];
      #pragma unroll 4
      for (int i = 0; i < CHUNK / 4; ++i) {
        const int q = (q0 + 4 * i) & (CHUNK - 1);
        const float4* p4 = (const float4*)(tp + (s * CHUNK + q) * 3);
        float4 v0 = p4[0], v1 = p4[1], v2 = p4[2];
        const float d0 = dist2(mx, my, mz, v0.x, v0.y, v0.z);
        const float d1 = dist2(mx, my, mz, v0.w, v1.x, v1.y);
        const float d2 = dist2(mx, my, mz, v1.z, v1.w, v2.x);
        const float d3 = dist2(mx, my, mz, v2.y, v2.z, v2.w);
        ins(d0); ins(d1); ins(d2); ins(d3);
      }
      if (more) {
        if (has) ((float4*)tiles[cur ^ 1])[tid] = rn;
        __syncthreads();
        cur ^= 1;
      }
    }
  }
  #pragma unroll
  for (int i = 0; i < M; ++i) smin[g][s * M + i] = nd[M - 1 - i];  // ascending
  __syncthreads();

  // restage tile 0 + zero counters (overlaps merge compute below)
  if (has) ((float4*)tiles[0])[tid] = gx0[tid];
  if (tid < PPB) { pc[tid] = 0; pk[tid] = 0; }

  // ---- Merge: tau_hat = 21st smallest of the 48-union (>= true tau; exactly
  //      one self-zero is in the union). Parallel rank-select: each thread
  //      ranks its own 3 values; the holder of 0-based index 20 writes tau. ---
  {
    const float* L = &smin[g][0];
    const float v0 = L[3 * s], v1 = L[3 * s + 1], v2 = L[3 * s + 2];
    int lt0 = 0, le0 = 0, lt1 = 0, le1 = 0, lt2 = 0, le2 = 0;
    #pragma unroll 4
    for (int j = 0; j < SUBS * M; ++j) {
      const float u = L[j];
      lt0 += (u <  v0); le0 += (u <= v0);
      lt1 += (u <  v1); le1 += (u <= v1);
      lt2 += (u <  v2); le2 += (u <= v2);
    }
    if (lt0 <= KK && KK < le0) taub[g] = v0;
    if (lt1 <= KK && KK < le1) taub[g] = v1;
    if (lt2 <= KK && KK < le2) taub[g] = v2;
  }
  __syncthreads();   // tile 0 staged, counters zeroed, taub written
  const float tau = taub[g];

  // ---------------- Phase B: collect candidates d <= tau (self included) -----
  {
    int cur = 0;
    for (int t = 0; t < NT; ++t) {
      float4 rn;
      const bool more = (t + 1 < NT);
      if (more && has) rn = gx0[(t + 1) * (TILE * 3 / 4) + tid];
      const float* tp = tiles[cur];
      const int jg0 = t * TILE + s * CHUNK;
      for (int i = 0; i < CHUNK / 4; ++i) {
        const int q = (q0 + 4 * i) & (CHUNK - 1);
        const float4* p4 = (const float4*)(tp + (s * CHUNK + q) * 3);
        float4 v0 = p4[0], v1 = p4[1], v2 = p4[2];
        const int jg = jg0 + q;
        const float d0 = dist2(mx, my, mz, v0.x, v0.y, v0.z);
        const float d1 = dist2(mx, my, mz, v0.w, v1.x, v1.y);
        const float d2 = dist2(mx, my, mz, v1.z, v1.w, v2.x);
        const float d3 = dist2(mx, my, mz, v2.y, v2.z, v2.w);
        if (d0 <= tau) { int w = atomicAdd(&pc[g], 1); if (w < CAP) { dcand[g][w] = d0; jcand[g][w] = jg + 0; } }
        if (d1 <= tau) { int w = atomicAdd(&pc[g], 1); if (w < CAP) { dcand[g][w] = d1; jcand[g][w] = jg + 1; } }
        if (d2 <= tau) { int w = atomicAdd(&pc[g], 1); if (w < CAP) { dcand[g][w] = d2; jcand[g][w] = jg + 2; } }
        if (d3 <= tau) { int w = atomicAdd(&pc[g], 1); if (w < CAP) { dcand[g][w] = d3; jcand[g][w] = jg + 3; } }
      }
      if (more) {
        if (has) ((float4*)tiles[cur ^ 1])[tid] = rn;
        __syncthreads();
        cur ^= 1;
      }
    }
  }
  __syncthreads();

  // ---- Rank + compact: keep j != self with lex-rank(d, j) <= 20 (exactly 20;
  //      matches top_k's low-index tie-break; set is deterministic) -----------
  int (*jkeep)[CROW] = (int(*)[CROW])smin;             // smin dead after merge
  {
    const int n0 = pc[g];
    const int n = n0 < CAP ? n0 : CAP;
    for (int k = s; k < n; k += SUBS) {
      const float dk = dcand[g][k];
      const int   jk = jcand[g][k];
      int rank = 0;
      for (int k2 = 0; k2 < n; ++k2) {
        const float d2 = dcand[g][k2];
        const int   j2 = jcand[g][k2];
        rank += (d2 < dk || (d2 == dk && j2 < jk)) ? 1 : 0;
      }
      if (jk != myp && rank <= KK) {
        const int w = atomicAdd(&pk[g], 1);
        jkeep[g][w] = jk;
      }
    }
  }
  __syncthreads();

  // ---------------- Feature phase: lane = channel; h = xj.w345 + const_i -----
  const int wv   = tid >> 6;           // wave 0..7
  const int lane = tid & 63;
  const float w3 = W[3*64+lane], w4 = W[4*64+lane], w5 = W[5*64+lane];
  const float c0 = W[0*64+lane] - w3;
  const float c1 = W[1*64+lane] - w4;
  const float c2 = W[2*64+lane] - w5;
  const float bo = bias[lane];

  for (int pi = 0; pi < PPB / 8; ++pi) {       // 4 points per wave
    const int p   = wv * (PPB / 8) + pi;
    const int pid = blk * PPB + p;
    const float* xi = x + (size_t)(base + pid) * 3;
    const float ci = fmaf(xi[0], c0, fmaf(xi[1], c1, fmaf(xi[2], c2, bo)));
    float hmax = -INFINITY;
    #pragma unroll 5
    for (int k = 0; k < KK; ++k) {             // exactly 20, wave-uniform
      const int j = jkeep[p][k];
      const float* xp = x + (size_t)(base + j) * 3;
      hmax = fmaxf(hmax, fmaf(xp[0], w3, fmaf(xp[1], w4, fmaf(xp[2], w5, ci))));
    }
    out[(size_t)(base + pid) * 64 + lane] = fmaxf(hmax, 0.0f);
  }
}

extern "C" void kernel_launch(void* const* d_in, const int* in_sizes, int n_in,
                              void* d_out, int out_size, void* d_ws, size_t ws_size,
                              hipStream_t stream) {
  const float* x  = (const float*)d_in[0];
  // d_in[1] = batch (implicit: i / N) — unused
  const float* W  = (const float*)d_in[2];
  const float* b  = (const float*)d_in[3];
  float* out = (float*)d_out;

  dim3 grid(8 * BPB);   // 1024 blocks: 8 batches x 128 point-groups
  dim3 block(BLK);
  hipLaunchKernelGGL(edgeconv_kernel, grid, block, 0, stream, x, W, b, out);
}